// Round 1
// baseline (623.418 us; speedup 1.0000x reference)
//
#include <hip/hip_runtime.h>
#include <math.h>

#define WW 1024
#define HH 1024
#define BB 16
#define PADR 10
#define TI 32
#define TJ 128
#define HALO_I (TI + 20)   // 52
#define HALO_J (TJ + 20)   // 148
#define PITCH 156          // LDS row pitch (floats); 156%4==0 for float4, spreads banks

// ---------------- prep: normalize PSF + scalar params into ws ----------------
__global__ void prep_kernel(const float* __restrict__ raw_psf,
                            const float* __restrict__ x0p, const float* __restrict__ y0p,
                            const float* __restrict__ raw_b, const float* __restrict__ raw_rc,
                            const float* __restrict__ raw_sub,
                            float* __restrict__ ws) {
    __shared__ float red[512];
    int t = threadIdx.x;
    float v = 0.f;
    if (t < 441) v = fmaxf(raw_psf[t], 0.f);
    red[t] = v;
    __syncthreads();
    for (int s = 256; s > 0; s >>= 1) {
        if (t < s) red[t] += red[t + s];
        __syncthreads();
    }
    float sum = fmaxf(red[0], 1e-12f);
    if (t < 441) ws[t] = v / sum;
    if (t == 0) {
        float b  = log1pf(expf(raw_b[0]))  + 1e-8f;
        float rc = log1pf(expf(raw_rc[0])) + 1e-8f;
        ws[441] = b;
        ws[442] = 1e-12f + rc * rc;   // EPS_R2 + rc^2 folded together
        ws[443] = 0.25f * tanhf(raw_sub[0]);
        ws[444] = 0.25f * tanhf(raw_sub[1]);
        ws[445] = x0p[0];
        ws[446] = y0p[0];
    }
}

// ---------------- fused warp (bilinear gather) + 21x21 conv ----------------
__global__ __launch_bounds__(256, 4) void fused_kernel(
        const float* __restrict__ src, const float* __restrict__ pp,
        float* __restrict__ out) {
    __shared__ float tile[HALO_I * PITCH];
    __shared__ float psf_s[441];

    const int tid = threadIdx.x;
    const int tile_j0 = blockIdx.x * TJ;   // y-dim of grid (contiguous in out)
    const int tile_i0 = blockIdx.y * TI;   // x-dim of grid
    const int b0 = blockIdx.z;

    const float bpar = pp[441];
    const float rc2  = pp[442];
    const float sub0 = pp[443];
    const float sub1 = pp[444];
    const float x0   = pp[445];
    const float y0   = pp[446];
    const float SSTEP = 2.0f / 1023.0f;

    for (int t = tid; t < 441; t += 256) psf_s[t] = pp[t];

    const float* sb = src + (size_t)b0 * (HH * WW);

    // ---- fill halo tile: warp sample at (I=x index, J=y index) ----
    for (int p = tid; p < HALO_I * HALO_J; p += 256) {
        int hr = p / HALO_J;          // i (x) within halo
        int hc = p - hr * HALO_J;     // j (y) within halo
        int I = tile_i0 - PADR + hr;
        int J = tile_j0 - PADR + hc;
        float val = 0.f;
        if ((unsigned)I < WW && (unsigned)J < HH) {
            float xv = fmaf((float)I, SSTEP, -1.0f);
            float yv = fmaf((float)J, SSTEP, -1.0f);
            float dx = xv - x0;
            float dy = yv - y0;
            float denom = sqrtf(dx * dx + dy * dy + rc2);
            float s = bpar / denom;
            float gx = xv - dx * s + sub0;
            float gy = yv - dy * s + sub1;
            float ix = (gx + 1.0f) * (0.5f * 1023.0f);
            float iy = (gy + 1.0f) * (0.5f * 1023.0f);
            float fx = floorf(ix), fy = floorf(iy);
            float wx1 = ix - fx, wy1 = iy - fy;
            float wx0 = 1.f - wx1, wy0 = 1.f - wy1;
            int xi0 = (int)fx, yi0 = (int)fy;
            int xi1 = xi0 + 1, yi1 = yi0 + 1;
            int xc0 = min(max(xi0, 0), WW - 1);
            int xc1 = min(max(xi1, 0), WW - 1);
            int yc0 = min(max(yi0, 0), HH - 1);
            int yc1 = min(max(yi1, 0), HH - 1);
            bool vx0 = (unsigned)xi0 < WW, vx1 = (unsigned)xi1 < WW;
            bool vy0 = (unsigned)yi0 < HH, vy1 = (unsigned)yi1 < HH;
            float w00 = (vx0 && vy0) ? wy0 * wx0 : 0.f;
            float w01 = (vx1 && vy0) ? wy0 * wx1 : 0.f;
            float w10 = (vx0 && vy1) ? wy1 * wx0 : 0.f;
            float w11 = (vx1 && vy1) ? wy1 * wx1 : 0.f;
            float v00 = sb[yc0 * WW + xc0];
            float v01 = sb[yc0 * WW + xc1];
            float v10 = sb[yc1 * WW + xc0];
            float v11 = sb[yc1 * WW + xc1];
            val = v00 * w00 + v01 * w01 + v10 * w10 + v11 * w11;
        }
        tile[hr * PITCH + hc] = val;
    }
    __syncthreads();

    // ---- conv: each thread computes 2 (i) x 8 (j) outputs ----
    const int jt = tid & 15;
    const int it = tid >> 4;
    const int li0 = it * 2;
    const int lj0 = jt * 8;

    float acc0[8], acc1[8];
#pragma unroll
    for (int c = 0; c < 8; ++c) { acc0[c] = 0.f; acc1[c] = 0.f; }

    float win0[28], win1[28];

#define LOADROW(dst, hr_) do {                                              \
        const float* r_ = &tile[(hr_) * PITCH + lj0];                       \
        _Pragma("unroll") for (int q = 0; q < 7; ++q) {                     \
            float4 f4 = *(const float4*)&r_[4 * q];                         \
            dst[4*q+0] = f4.x; dst[4*q+1] = f4.y;                           \
            dst[4*q+2] = f4.z; dst[4*q+3] = f4.w; }                         \
    } while (0)

#define TAPS(u_, rlow, rhigh) do {                                          \
        const float* prow_ = &psf_s[(u_) * 21];                            \
        _Pragma("unroll") for (int v = 0; v < 21; ++v) {                    \
            float pv_ = prow_[v];                                           \
            _Pragma("unroll") for (int c = 0; c < 8; ++c) {                 \
                acc0[c] = fmaf(pv_, rlow[v + c], acc0[c]);                  \
                acc1[c] = fmaf(pv_, rhigh[v + c], acc1[c]); } }             \
    } while (0)

    LOADROW(win0, li0);
#pragma unroll 1
    for (int uu = 0; uu < 10; ++uu) {
        int u = 2 * uu;
        LOADROW(win1, li0 + u + 1);
        TAPS(u, win0, win1);
        LOADROW(win0, li0 + u + 2);
        TAPS(u + 1, win1, win0);
    }
    LOADROW(win1, li0 + 21);
    TAPS(20, win0, win1);

#undef LOADROW
#undef TAPS

    // ---- store: out layout (B, 1, W, H): idx = b*W*H + i*H + j ----
    const int gi = tile_i0 + li0;
    const int gj = tile_j0 + lj0;
    float* ob = out + (size_t)b0 * (WW * HH) + (size_t)gi * HH + gj;
    *(float4*)&ob[0]      = make_float4(acc0[0], acc0[1], acc0[2], acc0[3]);
    *(float4*)&ob[4]      = make_float4(acc0[4], acc0[5], acc0[6], acc0[7]);
    *(float4*)&ob[HH]     = make_float4(acc1[0], acc1[1], acc1[2], acc1[3]);
    *(float4*)&ob[HH + 4] = make_float4(acc1[4], acc1[5], acc1[6], acc1[7]);
}

extern "C" void kernel_launch(void* const* d_in, const int* in_sizes, int n_in,
                              void* d_out, int out_size, void* d_ws, size_t ws_size,
                              hipStream_t stream) {
    const float* src     = (const float*)d_in[0];
    const float* raw_psf = (const float*)d_in[1];
    const float* x0      = (const float*)d_in[2];
    const float* y0      = (const float*)d_in[3];
    const float* raw_b   = (const float*)d_in[4];
    const float* raw_rc  = (const float*)d_in[5];
    const float* raw_sub = (const float*)d_in[6];
    float* ws = (float*)d_ws;

    prep_kernel<<<1, 512, 0, stream>>>(raw_psf, x0, y0, raw_b, raw_rc, raw_sub, ws);

    dim3 grid(HH / TJ, WW / TI, BB);   // (8, 32, 16)
    fused_kernel<<<grid, 256, 0, stream>>>(src, ws, (float*)d_out);
}

// Round 2
// 355.580 us; speedup vs baseline: 1.7532x; 1.7532x over previous
//
#include <hip/hip_runtime.h>
#include <math.h>

#define WW 1024
#define HH 1024
#define BB 16
#define PADR 10
#define TI 64            // output tile rows (i = x dim)
#define TJ 64            // output tile cols (j = y dim, contiguous in out)
#define HALO 84          // 64 + 20
#define PITCH 92         // LDS row pitch (floats), 4-aligned for float4

// ---------------- prep: normalize PSF + scalar params into ws ----------------
__global__ void prep_kernel(const float* __restrict__ raw_psf,
                            const float* __restrict__ x0p, const float* __restrict__ y0p,
                            const float* __restrict__ raw_b, const float* __restrict__ raw_rc,
                            const float* __restrict__ raw_sub,
                            float* __restrict__ ws) {
    __shared__ float red[512];
    int t = threadIdx.x;
    float v = 0.f;
    if (t < 441) v = fmaxf(raw_psf[t], 0.f);
    red[t] = v;
    __syncthreads();
    for (int s = 256; s > 0; s >>= 1) {
        if (t < s) red[t] += red[t + s];
        __syncthreads();
    }
    float sum = fmaxf(red[0], 1e-12f);
    if (t < 441) ws[t] = v / sum;
    if (t == 0) {
        float b  = log1pf(expf(raw_b[0]))  + 1e-8f;
        float rc = log1pf(expf(raw_rc[0])) + 1e-8f;
        ws[441] = b;
        ws[442] = 1e-12f + rc * rc;   // EPS_R2 + rc^2 folded
        ws[443] = 0.25f * tanhf(raw_sub[0]);
        ws[444] = 0.25f * tanhf(raw_sub[1]);
        ws[445] = x0p[0];
        ws[446] = y0p[0];
    }
}

// ---------------- fused warp (bilinear gather) + 21x21 conv ----------------
__global__ __launch_bounds__(256, 4) void fused_kernel(
        const float* __restrict__ src, const float* __restrict__ pp,
        float* __restrict__ out) {
    __shared__ float tile[HALO * PITCH];   // [I (x)][J (y)], 30.9 KB

    const int tid = threadIdx.x;
    const int tile_j0 = blockIdx.x * TJ;
    const int tile_i0 = blockIdx.y * TI;
    const int b0 = blockIdx.z;

    const float bpar = pp[441];
    const float rc2  = pp[442];
    const float sub0 = pp[443];
    const float sub1 = pp[444];
    const float x0   = pp[445];
    const float y0   = pp[446];
    const float SSTEP = 2.0f / 1023.0f;

    const float* sb = src + (size_t)b0 * (HH * WW);

    // ---- fill halo tile: warp sample at (I=x index, J=y index) ----
    for (int p = tid; p < HALO * HALO; p += 256) {
        int hc = p / HALO;            // J (y) within halo
        int hr = p - hc * HALO;       // I (x) within halo  (lane-consecutive)
        int I = tile_i0 - PADR + hr;
        int J = tile_j0 - PADR + hc;
        float val = 0.f;
        if ((unsigned)I < WW && (unsigned)J < HH) {
            float xv = fmaf((float)I, SSTEP, -1.0f);
            float yv = fmaf((float)J, SSTEP, -1.0f);
            float dx = xv - x0;
            float dy = yv - y0;
            float denom = sqrtf(dx * dx + dy * dy + rc2);
            float s = bpar / denom;
            float gx = xv - dx * s + sub0;
            float gy = yv - dy * s + sub1;
            float ix = (gx + 1.0f) * (0.5f * 1023.0f);
            float iy = (gy + 1.0f) * (0.5f * 1023.0f);
            float fx = floorf(ix), fy = floorf(iy);
            float wx1 = ix - fx, wy1 = iy - fy;
            float wx0 = 1.f - wx1, wy0 = 1.f - wy1;
            int xi0 = (int)fx, yi0 = (int)fy;
            int xi1 = xi0 + 1, yi1 = yi0 + 1;
            int xc0 = min(max(xi0, 0), WW - 1);
            int xc1 = min(max(xi1, 0), WW - 1);
            int yc0 = min(max(yi0, 0), HH - 1);
            int yc1 = min(max(yi1, 0), HH - 1);
            bool vx0 = (unsigned)xi0 < WW, vx1 = (unsigned)xi1 < WW;
            bool vy0 = (unsigned)yi0 < HH, vy1 = (unsigned)yi1 < HH;
            float w00 = (vx0 && vy0) ? wy0 * wx0 : 0.f;
            float w01 = (vx1 && vy0) ? wy0 * wx1 : 0.f;
            float w10 = (vx0 && vy1) ? wy1 * wx0 : 0.f;
            float w11 = (vx1 && vy1) ? wy1 * wx1 : 0.f;
            float v00 = sb[yc0 * WW + xc0];
            float v01 = sb[yc0 * WW + xc1];
            float v10 = sb[yc1 * WW + xc0];
            float v11 = sb[yc1 * WW + xc1];
            val = v00 * w00 + v01 * w01 + v10 * w10 + v11 * w11;
        }
        tile[hr * PITCH + hc] = val;
    }
    __syncthreads();

    // ---- conv: each thread computes 4 (i) x 4 (j) outputs ----
    const int jt = tid & 15;       // 16 j-groups
    const int it = tid >> 4;       // 16 i-groups
    const int li0 = it * 4;
    const int lj0 = jt * 4;

    float acc[4][4];
#pragma unroll
    for (int i = 0; i < 4; ++i)
#pragma unroll
        for (int c = 0; c < 4; ++c) acc[i][c] = 0.f;

    // stream 24 tile rows through a single 24-float register window;
    // psf taps read as wave-uniform global loads -> s_load + SGPR fma operand
#pragma unroll 1
    for (int r = 0; r < 24; ++r) {
        const float* rowp = &tile[(li0 + r) * PITCH + lj0];
        float win[24];
#pragma unroll
        for (int q = 0; q < 6; ++q) {
            float4 f = *(const float4*)&rowp[4 * q];
            win[4 * q + 0] = f.x; win[4 * q + 1] = f.y;
            win[4 * q + 2] = f.z; win[4 * q + 3] = f.w;
        }
#pragma unroll
        for (int i = 0; i < 4; ++i) {
            int u = r - i;
            if (u >= 0 && u <= 20) {           // wave-uniform branch
                const float* prow = pp + u * 21;
#pragma unroll
                for (int v = 0; v < 21; ++v) {
                    float pv = prow[v];
                    acc[i][0] = fmaf(pv, win[v + 0], acc[i][0]);
                    acc[i][1] = fmaf(pv, win[v + 1], acc[i][1]);
                    acc[i][2] = fmaf(pv, win[v + 2], acc[i][2]);
                    acc[i][3] = fmaf(pv, win[v + 3], acc[i][3]);
                }
            }
        }
    }

    // ---- store: out layout (B, 1, W, H): idx = b*W*H + i*H + j ----
    const int gi0 = tile_i0 + li0;
    const int gj0 = tile_j0 + lj0;
    float* ob = out + (size_t)b0 * (WW * HH) + (size_t)gi0 * HH + gj0;
#pragma unroll
    for (int i = 0; i < 4; ++i) {
        *(float4*)&ob[(size_t)i * HH] =
            make_float4(acc[i][0], acc[i][1], acc[i][2], acc[i][3]);
    }
}

extern "C" void kernel_launch(void* const* d_in, const int* in_sizes, int n_in,
                              void* d_out, int out_size, void* d_ws, size_t ws_size,
                              hipStream_t stream) {
    const float* src     = (const float*)d_in[0];
    const float* raw_psf = (const float*)d_in[1];
    const float* x0      = (const float*)d_in[2];
    const float* y0      = (const float*)d_in[3];
    const float* raw_b   = (const float*)d_in[4];
    const float* raw_rc  = (const float*)d_in[5];
    const float* raw_sub = (const float*)d_in[6];
    float* ws = (float*)d_ws;

    prep_kernel<<<1, 512, 0, stream>>>(raw_psf, x0, y0, raw_b, raw_rc, raw_sub, ws);

    dim3 grid(HH / TJ, WW / TI, BB);   // (16, 16, 16)
    fused_kernel<<<grid, 256, 0, stream>>>(src, ws, (float*)d_out);
}

// Round 3
// 266.592 us; speedup vs baseline: 2.3385x; 1.3338x over previous
//
#include <hip/hip_runtime.h>
#include <math.h>

#define WW 1024
#define HH 1024
#define TI 128
#define TJ 128
#define HALO_I 160     // hr (x) extent in LDS, padded; valid hr < 148
#define HALO_J 148     // hc (y) extent
#define PITCH_T 168    // ThT row pitch in elems; 336B -> conflict-free b128 phases
#define AOFF 448       // float offset of A-pattern table in ws

typedef short short8 __attribute__((ext_vector_type(8)));
typedef float float16 __attribute__((ext_vector_type(16)));

__device__ __forceinline__ unsigned short f2bf(float f) {
    union { float f; unsigned int u; } c; c.f = f;
    unsigned int u = c.u;
    return (unsigned short)((u + 0x7FFFu + ((u >> 16) & 1u)) >> 16);
}

// ---------------- prep: PSF normalize, params, Toeplitz A-pattern table ------
// A-pattern: for chunk-offset d in [0,4), lane l (m=l&31, k0=8*(l>>5)),
//   Apat[v][d][l][q] = P_bf16[16d + k0 + q - m][v]   (0 if u outside [0,20])
// Layout lane-major so each lane's 8 bf16 are one contiguous 16B read.
__global__ void prep_kernel(const float* __restrict__ raw_psf,
                            const float* __restrict__ x0p, const float* __restrict__ y0p,
                            const float* __restrict__ raw_b, const float* __restrict__ raw_rc,
                            const float* __restrict__ raw_sub,
                            float* __restrict__ ws) {
    __shared__ float red[512];
    __shared__ float psn[441];
    int t = threadIdx.x;
    float v = 0.f;
    if (t < 441) v = fmaxf(raw_psf[t], 0.f);
    red[t] = v;
    __syncthreads();
    for (int s = 256; s > 0; s >>= 1) {
        if (t < s) red[t] += red[t + s];
        __syncthreads();
    }
    float sum = fmaxf(red[0], 1e-12f);
    if (t < 441) { float pn = v / sum; ws[t] = pn; psn[t] = pn; }
    if (t == 0) {
        float b  = log1pf(expf(raw_b[0]))  + 1e-8f;
        float rc = log1pf(expf(raw_rc[0])) + 1e-8f;
        ws[441] = b;
        ws[442] = 1e-12f + rc * rc;
        ws[443] = 0.25f * tanhf(raw_sub[0]);
        ws[444] = 0.25f * tanhf(raw_sub[1]);
        ws[445] = x0p[0];
        ws[446] = y0p[0];
    }
    __syncthreads();

    short* A = (short*)(ws + AOFF);
    for (int g = t; g < 21 * 256; g += 512) {      // g = v*256 + d*64 + l
        int vv = g >> 8;
        int r  = g & 255;
        int d  = r >> 6;
        int l  = r & 63;
        int m  = l & 31;
        int k0 = (l >> 5) << 3;
        short8 o8;
#pragma unroll
        for (int q = 0; q < 8; ++q) {
            int u = 16 * d + k0 + q - m;
            unsigned short pv = 0;
            if ((unsigned)u <= 20u) pv = f2bf(psn[u * 21 + vv]);
            o8[q] = (short)pv;
        }
        *(short8*)&A[(size_t)g * 8] = o8;
    }
}

// ---------------- fused: bilinear warp -> bf16 LDS (transposed) -> MFMA conv -
__global__ __launch_bounds__(256, 2) void fused_kernel(
        const float* __restrict__ src, const float* __restrict__ pp,
        float* __restrict__ out) {
    __shared__ unsigned short ThT[HALO_J * PITCH_T];   // [hc][hr], bf16

    const int tid = threadIdx.x;
    const int j0 = blockIdx.x * TJ;
    const int i0 = blockIdx.y * TI;
    const int b0 = blockIdx.z;

    const float bpar = pp[441];
    const float rc2  = pp[442];
    const float sub0 = pp[443];
    const float sub1 = pp[444];
    const float x0   = pp[445];
    const float y0   = pp[446];
    const float SSTEP = 2.0f / 1023.0f;

    const float* sb = src + (size_t)b0 * (HH * (size_t)WW);

    // ---- fill transposed halo tile (2 adjacent hr per thread, packed write) ----
    for (int p = tid; p < (HALO_J * HALO_I) / 2; p += 256) {
        int idx2 = p << 1;
        int hc = idx2 / HALO_I;
        int hr0 = idx2 - hc * HALO_I;
        unsigned int pk = 0;
#pragma unroll
        for (int e = 0; e < 2; ++e) {
            int hr = hr0 + e;
            int I = i0 - 10 + hr;        // x index
            int J = j0 - 10 + hc;        // y index
            float val = 0.f;
            if (hr < 148 && (unsigned)I < WW && (unsigned)J < HH) {
                float xv = fmaf((float)I, SSTEP, -1.0f);
                float yv = fmaf((float)J, SSTEP, -1.0f);
                float dx = xv - x0;
                float dy = yv - y0;
                float s = bpar * __builtin_amdgcn_rsqf(dx * dx + dy * dy + rc2);
                float gx = xv - dx * s + sub0;
                float gy = yv - dy * s + sub1;
                float ix = (gx + 1.0f) * (0.5f * 1023.0f);
                float iy = (gy + 1.0f) * (0.5f * 1023.0f);
                float fx = floorf(ix), fy = floorf(iy);
                float wx1 = ix - fx, wy1 = iy - fy;
                float wx0 = 1.f - wx1, wy0 = 1.f - wy1;
                int xi0 = (int)fx, yi0 = (int)fy;
                int xi1 = xi0 + 1, yi1 = yi0 + 1;
                int xc0 = min(max(xi0, 0), WW - 1);
                int xc1 = min(max(xi1, 0), WW - 1);
                int yc0 = min(max(yi0, 0), HH - 1);
                int yc1 = min(max(yi1, 0), HH - 1);
                bool vx0 = (unsigned)xi0 < WW, vx1 = (unsigned)xi1 < WW;
                bool vy0 = (unsigned)yi0 < HH, vy1 = (unsigned)yi1 < HH;
                float w00 = (vx0 && vy0) ? wy0 * wx0 : 0.f;
                float w01 = (vx1 && vy0) ? wy0 * wx1 : 0.f;
                float w10 = (vx0 && vy1) ? wy1 * wx0 : 0.f;
                float w11 = (vx1 && vy1) ? wy1 * wx1 : 0.f;
                float v00 = sb[yc0 * WW + xc0];
                float v01 = sb[yc0 * WW + xc1];
                float v10 = sb[yc1 * WW + xc0];
                float v11 = sb[yc1 * WW + xc1];
                val = v00 * w00 + v01 * w01 + v10 * w10 + v11 * w11;
            }
            pk |= (unsigned int)f2bf(val) << (16 * e);
        }
        *(unsigned int*)&ThT[hc * PITCH_T + hr0] = pk;
    }
    __syncthreads();

    // ---- MFMA conv: wave wv owns j in [32*wv, 32*wv+32), all 4 M-blocks ----
    const int lane = tid & 63;
    const int wv = tid >> 6;
    const int nrow = lane & 31;          // n (j) for B and C; m (i) for A
    const int khalf = lane >> 5;

    float16 acc[4];
#pragma unroll
    for (int m = 0; m < 4; ++m)
#pragma unroll
        for (int q = 0; q < 16; ++q) acc[m][q] = 0.f;

    const short8* Aall = (const short8*)(pp + AOFF);

#pragma unroll 1
    for (int v = 0; v < 21; ++v) {
        short8 Af[4];
#pragma unroll
        for (int d = 0; d < 4; ++d)
            Af[d] = Aall[(v * 4 + d) * 64 + lane];     // L2-resident, shared by all blocks

        const unsigned short* bp = &ThT[(32 * wv + nrow + v) * PITCH_T + khalf * 8];
        short8 Bf[10];
#pragma unroll
        for (int c = 0; c < 10; ++c)
            Bf[c] = *(const short8*)&bp[16 * c];

#pragma unroll
        for (int mq = 0; mq < 4; ++mq) {
#pragma unroll
            for (int d = 0; d < 4; ++d)
                acc[mq] = __builtin_amdgcn_mfma_f32_32x32x16_bf16(
                    Af[d], Bf[2 * mq + d], acc[mq], 0, 0, 0);
        }
    }

    // ---- epilogue: C/D layout col=lane&31, row=(reg&3)+8*(reg>>2)+4*(lane>>5) ----
    float* ob = out + (size_t)b0 * (WW * (size_t)HH);
    const int gj = j0 + 32 * wv + nrow;
#pragma unroll
    for (int mq = 0; mq < 4; ++mq) {
#pragma unroll
        for (int reg = 0; reg < 16; ++reg) {
            int row = (reg & 3) + 8 * (reg >> 2) + 4 * khalf;
            int gi = i0 + 32 * mq + row;
            ob[(size_t)gi * HH + gj] = acc[mq][reg];
        }
    }
}

extern "C" void kernel_launch(void* const* d_in, const int* in_sizes, int n_in,
                              void* d_out, int out_size, void* d_ws, size_t ws_size,
                              hipStream_t stream) {
    const float* src     = (const float*)d_in[0];
    const float* raw_psf = (const float*)d_in[1];
    const float* x0      = (const float*)d_in[2];
    const float* y0      = (const float*)d_in[3];
    const float* raw_b   = (const float*)d_in[4];
    const float* raw_rc  = (const float*)d_in[5];
    const float* raw_sub = (const float*)d_in[6];
    float* ws = (float*)d_ws;

    prep_kernel<<<1, 512, 0, stream>>>(raw_psf, x0, y0, raw_b, raw_rc, raw_sub, ws);

    dim3 grid(HH / TJ, WW / TI, 16);   // (8, 8, 16)
    fused_kernel<<<grid, 256, 0, stream>>>(src, ws, (float*)d_out);
}